// Round 1
// baseline (225.078 us; speedup 1.0000x reference)
//
#include <hip/hip_runtime.h>

// Net_3152505995417: tiny GNN forward on the AAL connectome.
// N=116 nodes, E=6670 edges (full upper triangle), HID=64, EDIM=5.
// Key algebraic collapses (see session journal):
//  * node_conv: A[i,j] = d[eid(i,j)] off-diag  ->  out = D @ (Hv @ W), D sym NxN
//  * edge_conv: mult[e,f] = dv[shared node]; colmax[f=(c,d)] = max(dv[c],dv[d],0);
//      out[e=(a,b)] = dv[a]*(S[a]-Gp[e]) + dv[b]*(S[b]-Gp[e]),
//      Gp[f] = G[f]/(colmax[f]+eps), S[i] = sum_{f∋i} Gp[f]
//    => O(E*EDIM) instead of O(E^2).

#define NN   116
#define EE   6670
#define HID  64
#define EDIM 5
#define OUTD 4
#define ENC  122
#define EPSF 1e-10f
#define NH   (NN*HID)   // 7424

__device__ __forceinline__ int eid_ij(int i, int j) {
    int a = i < j ? i : j;
    int b = i < j ? j : i;
    // triu_indices(N, k=1) row-major order
    return a*NN - ((a*(a+1)) >> 1) + (b - a - 1);
}

// K1: x = enc @ W_enc + b_enc ; d1 = edge_attr @ p1 ; G = relu(edge_attr) @ We
__global__ void k1(const float* __restrict__ enc, const float* __restrict__ ea,
                   const float* __restrict__ W_enc, const float* __restrict__ b_enc,
                   const float* __restrict__ p1, const float* __restrict__ We,
                   float* __restrict__ X, float* __restrict__ d1, float* __restrict__ G)
{
    int t = blockIdx.x*blockDim.x + threadIdx.x;
    if (t < NH) {
        int i = t >> 6, h = t & 63;
        float acc = b_enc[h];
        const float* er = enc + i*ENC;
        #pragma unroll 2
        for (int k = 0; k < ENC; ++k) acc = fmaf(er[k], W_enc[k*HID + h], acc);
        X[t] = acc;
    } else if (t < NH + EE) {
        int e = t - NH;
        const float* r = ea + e*EDIM;
        float acc = 0.f;
        #pragma unroll
        for (int k = 0; k < EDIM; ++k) acc = fmaf(r[k], p1[k], acc);
        d1[e] = acc;
    } else if (t < NH + EE + EE*EDIM) {
        int idx = t - NH - EE;
        int e = idx / EDIM, k = idx - e*EDIM;
        const float* r = ea + e*EDIM;
        float acc = 0.f;
        #pragma unroll
        for (int m = 0; m < EDIM; ++m) acc = fmaf(fmaxf(r[m], 0.f), We[m*EDIM + k], acc);
        G[idx] = acc;
    }
}

// K2: Y1 = x @ W1
__global__ void k2(const float* __restrict__ X, const float* __restrict__ W1,
                   float* __restrict__ Y)
{
    int t = blockIdx.x*blockDim.x + threadIdx.x;   // grid == NH exactly
    int i = t >> 6, h = t & 63;
    float acc = 0.f;
    const float* xr = X + i*HID;
    #pragma unroll 4
    for (int k = 0; k < HID; ++k) acc = fmaf(xr[k], W1[k*HID + h], acc);
    Y[t] = acc;
}

// K3: x2 = relu(D1 @ Y1 + b1); dv[i] = x2[i,:] . pe  (wave64 reduction, one row per wave)
__global__ void k3(const float* __restrict__ d1, const float* __restrict__ Y,
                   const float* __restrict__ b1, const float* __restrict__ pe,
                   float* __restrict__ X2, float* __restrict__ dv)
{
    int t = blockIdx.x*blockDim.x + threadIdx.x;   // grid == NH exactly (29 blocks x 256)
    int i = t >> 6, h = t & 63;
    float acc = b1[h];
    #pragma unroll 4
    for (int j = 0; j < NN; ++j) {
        if (j == i) continue;
        acc = fmaf(d1[eid_ij(i, j)], Y[j*HID + h], acc);
    }
    float v = fmaxf(acc, 0.f);
    X2[t] = v;
    float r = v * pe[h];
    for (int off = 32; off > 0; off >>= 1) r += __shfl_down(r, off, 64);
    if (h == 0) dv[i] = r;
}

// K4: S[i,k] = sum_{j != i} G[eid(i,j),k] / (max(dv[i],dv[j],0)+eps)
__global__ void k4(const float* __restrict__ G, const float* __restrict__ dv,
                   float* __restrict__ S)
{
    int t = blockIdx.x*blockDim.x + threadIdx.x;
    if (t >= NN*EDIM) return;
    int i = t / EDIM, k = t - i*EDIM;
    float di = dv[i];
    float acc = 0.f;
    for (int j = 0; j < NN; ++j) {
        if (j == i) continue;
        float cm = fmaxf(fmaxf(di, dv[j]), 0.f) + EPSF;
        acc += G[eid_ij(i, j)*EDIM + k] / cm;
    }
    S[t] = acc;
}

// K5: per-edge e=(a,b): e2 = relu(dv[a]*(S[a]-Gp) + dv[b]*(S[b]-Gp) + be); d2 = e2 . p2
//     plus (block-split) Y2 = x2 @ W2
__global__ void k5(const int* __restrict__ eidx, const float* __restrict__ G,
                   const float* __restrict__ dv, const float* __restrict__ S,
                   const float* __restrict__ be, const float* __restrict__ p2,
                   const float* __restrict__ X2, const float* __restrict__ W2,
                   float* __restrict__ d2, float* __restrict__ Y)
{
    int t = blockIdx.x*blockDim.x + threadIdx.x;
    if (t < EE) {
        int a = eidx[t], b = eidx[EE + t];
        float da = dv[a], db = dv[b];
        float rc = 1.f / (fmaxf(fmaxf(da, db), 0.f) + EPSF);
        float acc = 0.f;
        #pragma unroll
        for (int k = 0; k < EDIM; ++k) {
            float gp = G[t*EDIM + k] * rc;
            float v = fmaf(da, S[a*EDIM + k] - gp, fmaf(db, S[b*EDIM + k] - gp, be[k]));
            acc = fmaf(fmaxf(v, 0.f), p2[k], acc);
        }
        d2[t] = acc;
    } else if (t < EE + NH) {
        int u = t - EE;
        int i = u >> 6, h = u & 63;
        float acc = 0.f;
        const float* xr = X2 + i*HID;
        #pragma unroll 4
        for (int k = 0; k < HID; ++k) acc = fmaf(xr[k], W2[k*HID + h], acc);
        Y[u] = acc;
    }
}

// K6: x3 = D2 @ Y2 + b2
__global__ void k6(const float* __restrict__ d2, const float* __restrict__ Y,
                   const float* __restrict__ b2, float* __restrict__ X3)
{
    int t = blockIdx.x*blockDim.x + threadIdx.x;   // grid == NH exactly
    int i = t >> 6, h = t & 63;
    float acc = b2[h];
    #pragma unroll 4
    for (int j = 0; j < NN; ++j) {
        if (j == i) continue;
        acc = fmaf(d2[eid_ij(i, j)], Y[j*HID + h], acc);
    }
    X3[t] = acc;
}

// K7: pooled = mean over nodes; out = pooled @ Wl + bl   (single 64-thread block)
__global__ void k7(const float* __restrict__ X3, const float* __restrict__ Wl,
                   const float* __restrict__ bl, float* __restrict__ out)
{
    __shared__ float ph[HID];
    int t = threadIdx.x;  // 64 threads
    float acc = 0.f;
    for (int i = 0; i < NN; ++i) acc += X3[i*HID + t];
    ph[t] = acc * (1.0f / NN);
    __syncthreads();
    if (t < OUTD) {
        float o = bl[t];
        for (int h = 0; h < HID; ++h) o = fmaf(ph[h], Wl[h*OUTD + t], o);
        out[t] = o;
    }
}

extern "C" void kernel_launch(void* const* d_in, const int* in_sizes, int n_in,
                              void* d_out, int out_size, void* d_ws, size_t ws_size,
                              hipStream_t stream)
{
    const float* enc   = (const float*)d_in[0];
    const float* ea    = (const float*)d_in[1];
    const int*   eidx  = (const int*)  d_in[2];
    const float* W_enc = (const float*)d_in[3];
    const float* b_enc = (const float*)d_in[4];
    const float* W1    = (const float*)d_in[5];
    const float* b1    = (const float*)d_in[6];
    const float* p1    = (const float*)d_in[7];
    const float* We    = (const float*)d_in[8];
    const float* be    = (const float*)d_in[9];
    const float* pe    = (const float*)d_in[10];
    const float* W2    = (const float*)d_in[11];
    const float* b2    = (const float*)d_in[12];
    const float* p2    = (const float*)d_in[13];
    const float* Wl    = (const float*)d_in[14];
    const float* bl    = (const float*)d_in[15];
    float* ws = (float*)d_ws;

    // Workspace layout (floats), with lifetime-based aliasing:
    //  A_ [E]      : d1 (K1..K3), then d2 (K5..K6)
    //  G  [E*EDIM] : G  (K1..K5), then x3 (K6..K7, first NH floats)
    //  X  [NH]     : x  (K1..K2), then x2 (K3..K5)
    //  Y  [NH]     : Y1 (K2..K3), then Y2 (K5..K6)
    //  dv [N], S [N*EDIM]
    float* A_ = ws;                    // E
    float* G  = ws + EE;               // E*EDIM
    float* X  = ws + EE*(1 + EDIM);    // NH
    float* Y  = X + NH;                // NH
    float* dv = Y + NH;                // N
    float* S  = dv + NN;               // N*EDIM
    float* out = (float*)d_out;

    const int B = 256;
    k1<<<(NH + EE + EE*EDIM + B - 1)/B, B, 0, stream>>>(enc, ea, W_enc, b_enc, p1, We, X, A_, G);
    k2<<<NH/B, B, 0, stream>>>(X, W1, Y);
    k3<<<NH/B, B, 0, stream>>>(A_, Y, b1, pe, X, dv);
    k4<<<(NN*EDIM + B - 1)/B, B, 0, stream>>>(G, dv, S);
    k5<<<(EE + NH + B - 1)/B, B, 0, stream>>>(eidx, G, dv, S, be, p2, X, W2, A_, Y);
    k6<<<NH/B, B, 0, stream>>>(A_, Y, b2, G);
    k7<<<1, 64, 0, stream>>>(G, Wl, bl, out);
}

// Round 2
// 124.223 us; speedup vs baseline: 1.8119x; 1.8119x over previous
//
#include <hip/hip_runtime.h>

// Net_3152505995417: tiny GNN forward (N=116, E=6670, HID=64, EDIM=5).
// Algebraic collapses (exact, verified absmax=0 in R1):
//  * node_conv: out = D @ (Hv@W) + b, D[i,j] = d[eid(i,j)] off-diag (sym).
//  * edge_conv: out[e=(a,b),k] = dv[a]*(S[a,k]-Gp[e,k]) + dv[b]*(S[b,k]-Gp[e,k]) + be,
//      Gp[f] = G[f]/(max(dv[c],dv[d],0)+eps) for f=(c,d), S[i] = sum_{f∋i} Gp[f].
// R2: latency-bound fixes — LDS-staged branchless node-conv loops, wave-parallel S,
//     fused X->Y1 and x2->{dv,Y2}, fused pooling via atomics. 6 dispatches.

#define NN   116
#define EE   6670
#define HID  64
#define EDIM 5
#define OUTD 4
#define ENC  122
#define EPSF 1e-10f
#define NH   (NN*HID)   // 7424

__device__ __forceinline__ int eid_ij(int i, int j) {
    int a = i < j ? i : j;
    int b = i < j ? j : i;
    return a*NN - ((a*(a+1)) >> 1) + (b - a - 1);   // triu k=1 row-major
}

// KA: node blocks (0..28): X row = enc@W_enc+b_enc (LDS), Y1 row = Xrow@W1.
//     edge blocks (29..): d1 = ea@p1 ; G = relu(ea)@We.
__global__ __launch_bounds__(256) void kA(
    const float* __restrict__ enc, const float* __restrict__ ea,
    const float* __restrict__ W_enc, const float* __restrict__ b_enc,
    const float* __restrict__ p1, const float* __restrict__ We,
    const float* __restrict__ W1,
    float* __restrict__ Y1, float* __restrict__ d1, float* __restrict__ G)
{
    const int tid = threadIdx.x;
    if (blockIdx.x < 29) {
        __shared__ __align__(16) float sWe[ENC*HID];   // 31232 B
        __shared__ __align__(16) float sW1[HID*HID];   // 16384 B
        __shared__ __align__(16) float sEnc[4*ENC];    //  1952 B
        __shared__ float sX[4*HID];
        // burst staging, no dependent chains
        {
            const float4* g4 = (const float4*)W_enc; float4* s4 = (float4*)sWe;
            for (int u = tid; u < ENC*HID/4; u += 256) s4[u] = g4[u];
        }
        {
            const float4* g4 = (const float4*)W1; float4* s4 = (float4*)sW1;
            for (int u = tid; u < HID*HID/4; u += 256) s4[u] = g4[u];
        }
        {
            const float4* g4 = (const float4*)(enc + blockIdx.x*4*ENC); // 1952B-aligned
            float4* s4 = (float4*)sEnc;
            for (int u = tid; u < 4*ENC/4; u += 256) s4[u] = g4[u];
        }
        __syncthreads();
        const int w = tid >> 6, h = tid & 63;
        const int i = blockIdx.x*4 + w;
        float acc = b_enc[h];
        const float* er = sEnc + w*ENC;
        #pragma unroll 4
        for (int k = 0; k < ENC; ++k) acc = fmaf(er[k], sWe[k*HID + h], acc);
        sX[w*HID + h] = acc;
        __syncthreads();
        float a2 = 0.f;
        const float* xr = sX + w*HID;
        #pragma unroll 8
        for (int k = 0; k < HID; ++k) a2 = fmaf(xr[k], sW1[k*HID + h], a2);
        Y1[i*HID + h] = a2;
    } else {
        int u = (blockIdx.x - 29)*256 + tid;
        if (u < EE) {
            const float* r = ea + u*EDIM;
            float a0 = 0.f;
            #pragma unroll
            for (int k = 0; k < EDIM; ++k) a0 = fmaf(r[k], p1[k], a0);
            d1[u] = a0;
        } else if (u < EE + EE*EDIM) {
            int idx = u - EE;
            int e = idx / EDIM, k = idx - e*EDIM;
            const float* r = ea + e*EDIM;
            float a0 = 0.f;
            #pragma unroll
            for (int m = 0; m < EDIM; ++m) a0 = fmaf(fmaxf(r[m], 0.f), We[m*EDIM + k], a0);
            G[idx] = a0;
        }
    }
}

// KB: x2 row = relu(D1@Y1 + b1) (LDS-staged, branchless); dv[i] = x2row.pe;
//     Y2 row = x2row @ W2.  4 nodes per 256-thread block, 29 blocks.
__global__ __launch_bounds__(256) void kB(
    const float* __restrict__ d1, const float* __restrict__ Y1,
    const float* __restrict__ b1, const float* __restrict__ pe,
    const float* __restrict__ W2,
    float* __restrict__ dv, float* __restrict__ Y2)
{
    __shared__ __align__(16) float sY[NH];   // 29696 B
    __shared__ __align__(16) float sD[EE];   // 26680 B
    __shared__ float sX2[4*HID];
    const int tid = threadIdx.x;
    {
        const float4* g4 = (const float4*)Y1; float4* s4 = (float4*)sY;
        for (int u = tid; u < NH/4; u += 256) s4[u] = g4[u];
        const float2* g2 = (const float2*)d1; float2* s2 = (float2*)sD;
        for (int u = tid; u < EE/2; u += 256) s2[u] = g2[u];
    }
    __syncthreads();
    const int w = tid >> 6, h = tid & 63;
    const int i = blockIdx.x*4 + w;
    float acc = b1[h];
    #pragma unroll 4
    for (int j = 0; j < NN; ++j) {
        int jj = (j == i) ? (j ^ 1) : j;
        float wgt = (j == i) ? 0.f : sD[eid_ij(i, jj)];
        acc = fmaf(wgt, sY[jj*HID + h], acc);
    }
    float v = fmaxf(acc, 0.f);
    float r = v * pe[h];
    #pragma unroll
    for (int off = 32; off > 0; off >>= 1) r += __shfl_down(r, off, 64);
    if (h == 0) dv[i] = r;
    sX2[w*HID + h] = v;
    __syncthreads();
    float a2 = 0.f;
    const float* xr = sX2 + w*HID;
    #pragma unroll 8
    for (int k = 0; k < HID; ++k) a2 = fmaf(xr[k], W2[k*HID + h], a2);
    Y2[i*HID + h] = a2;
}

// KC: S[i,k] = sum_{j!=i} G[eid(i,j),k] / (max(dv[i],dv[j],0)+eps)
//     one wave per (i,k): 580 waves = 145 blocks x 256. Lanes split j.
__global__ __launch_bounds__(256) void kC(
    const float* __restrict__ G, const float* __restrict__ dv,
    float* __restrict__ S)
{
    const int wg = blockIdx.x*4 + (threadIdx.x >> 6);   // 0..579
    const int lane = threadIdx.x & 63;
    const int i = wg / EDIM, k = wg - i*EDIM;
    const float di = dv[i];
    float acc = 0.f;
    #pragma unroll
    for (int rep = 0; rep < 2; ++rep) {
        int j = lane + rep*64;
        if (j < NN && j != i) {
            float cm = fmaxf(fmaxf(di, dv[j]), 0.f) + EPSF;
            acc += G[eid_ij(i, j)*EDIM + k] / cm;
        }
    }
    #pragma unroll
    for (int off = 32; off > 0; off >>= 1) acc += __shfl_down(acc, off, 64);
    if (lane == 0) S[wg] = acc;
}

// KD: per-edge e=(a,b): d2[e] = relu(dv a/b combo) . p2 ; also zero P.
__global__ __launch_bounds__(256) void kD(
    const int* __restrict__ eidx, const float* __restrict__ G,
    const float* __restrict__ dv, const float* __restrict__ S,
    const float* __restrict__ be, const float* __restrict__ p2,
    float* __restrict__ d2, float* __restrict__ P)
{
    const int t = blockIdx.x*256 + threadIdx.x;
    if (blockIdx.x == 0 && threadIdx.x < HID) P[threadIdx.x] = 0.f;
    if (t >= EE) return;
    const int a = eidx[t], b = eidx[EE + t];
    const float da = dv[a], db = dv[b];
    const float rc = 1.f / (fmaxf(fmaxf(da, db), 0.f) + EPSF);
    float acc = 0.f;
    #pragma unroll
    for (int kk = 0; kk < EDIM; ++kk) {
        float gp = G[t*EDIM + kk] * rc;
        float v = fmaf(da, S[a*EDIM + kk] - gp, fmaf(db, S[b*EDIM + kk] - gp, be[kk]));
        acc = fmaf(fmaxf(v, 0.f), p2[kk], acc);
    }
    d2[t] = acc;
}

// KE: x3 row = D2@Y2 + b2 (LDS-staged, branchless); block-partial pooling -> atomicAdd P.
__global__ __launch_bounds__(256) void kE(
    const float* __restrict__ d2, const float* __restrict__ Y2,
    const float* __restrict__ b2, float* __restrict__ P)
{
    __shared__ __align__(16) float sY[NH];
    __shared__ __align__(16) float sD[EE];
    __shared__ float sR[4*HID];
    const int tid = threadIdx.x;
    {
        const float4* g4 = (const float4*)Y2; float4* s4 = (float4*)sY;
        for (int u = tid; u < NH/4; u += 256) s4[u] = g4[u];
        const float2* g2 = (const float2*)d2; float2* s2 = (float2*)sD;
        for (int u = tid; u < EE/2; u += 256) s2[u] = g2[u];
    }
    __syncthreads();
    const int w = tid >> 6, h = tid & 63;
    const int i = blockIdx.x*4 + w;
    float acc = b2[h];
    #pragma unroll 4
    for (int j = 0; j < NN; ++j) {
        int jj = (j == i) ? (j ^ 1) : j;
        float wgt = (j == i) ? 0.f : sD[eid_ij(i, jj)];
        acc = fmaf(wgt, sY[jj*HID + h], acc);
    }
    sR[w*HID + h] = acc;
    __syncthreads();
    if (w == 0) {
        float s4 = sR[h] + sR[HID + h] + sR[2*HID + h] + sR[3*HID + h];
        atomicAdd(&P[h], s4);
    }
}

// KF: out = (P/N) @ Wl + bl. One wave.
__global__ void kF(const float* __restrict__ P, const float* __restrict__ Wl,
                   const float* __restrict__ bl, float* __restrict__ out)
{
    const int lane = threadIdx.x;  // 64
    float val = P[lane] * (1.0f / NN);
    float res[OUTD];
    #pragma unroll
    for (int o = 0; o < OUTD; ++o) {
        float r = val * Wl[lane*OUTD + o];
        #pragma unroll
        for (int off = 32; off > 0; off >>= 1) r += __shfl_xor(r, off, 64);
        res[o] = r;
    }
    if (lane < OUTD) out[lane] = res[lane] + bl[lane];
}

extern "C" void kernel_launch(void* const* d_in, const int* in_sizes, int n_in,
                              void* d_out, int out_size, void* d_ws, size_t ws_size,
                              hipStream_t stream)
{
    const float* enc   = (const float*)d_in[0];
    const float* ea    = (const float*)d_in[1];
    const int*   eidx  = (const int*)  d_in[2];
    const float* W_enc = (const float*)d_in[3];
    const float* b_enc = (const float*)d_in[4];
    const float* W1    = (const float*)d_in[5];
    const float* b1    = (const float*)d_in[6];
    const float* p1    = (const float*)d_in[7];
    const float* We    = (const float*)d_in[8];
    const float* be    = (const float*)d_in[9];
    const float* pe    = (const float*)d_in[10];
    const float* W2    = (const float*)d_in[11];
    const float* b2    = (const float*)d_in[12];
    const float* p2    = (const float*)d_in[13];
    const float* Wl    = (const float*)d_in[14];
    const float* bl    = (const float*)d_in[15];
    float* ws = (float*)d_ws;

    // Workspace (floats), lifetime-aliased:
    //  Y1 @ 0      [NH]    : Y1 (KA..KB); P aliases Y1[0:64] (KD zeroes, KE adds, KF reads)
    //  Y2 @ 7424   [NH]    : Y2 (KB..KE)
    //  dA @ 14848  [EE]    : d1 (KA..KB), then d2 (KD..KE)
    //  G  @ 21518  [EE*5]  : G (KA..KD)
    //  dv @ 54868  [NN]
    //  S  @ 54984  [NN*5]
    float* Y1 = ws;
    float* P  = ws;            // aliases Y1 (dead after KB)
    float* Y2 = ws + NH;
    float* dA = ws + 2*NH;
    float* G  = dA + EE;
    float* dv = G + EE*EDIM;
    float* S  = dv + NN;
    float* out = (float*)d_out;

    kA<<<29 + (EE + EE*EDIM + 255)/256, 256, 0, stream>>>(enc, ea, W_enc, b_enc, p1, We, W1, Y1, dA, G);
    kB<<<29, 256, 0, stream>>>(dA, Y1, b1, pe, W2, dv, Y2);
    kC<<<(NN*EDIM)/4, 256, 0, stream>>>(G, dv, S);
    kD<<<(EE + 255)/256, 256, 0, stream>>>(eidx, G, dv, S, be, p2, dA, P);
    kE<<<29, 256, 0, stream>>>(dA, Y2, b2, P);
    kF<<<1, 64, 0, stream>>>(P, Wl, bl, out);
}